// Round 7
// baseline (323.036 us; speedup 1.0000x reference)
//
#include <hip/hip_runtime.h>

// Problem constants
#define B_  64
#define S_  512
#define D_  768
#define H_  768
#define C_  5
#define M_  (B_ * S_)        // 32768 rows

typedef float f32x4 __attribute__((ext_vector_type(4)));
typedef short short8 __attribute__((ext_vector_type(8)));   // bf16x8 MFMA operand

#define W1T_ELEMS (D_ * H_)      // 589824  (bf16: 1.18 MB)
#define XBF_ELEMS (M_ * D_)      // 25165824 (bf16: 50.33 MB)

__device__ __forceinline__ unsigned short f2bf(float f) {
    unsigned int u = __float_as_uint(f);
    u += 0x7FFFu + ((u >> 16) & 1u);     // RNE
    return (unsigned short)(u >> 16);
}

// =========================================================================
// Kernel 1: init pot = b2 + boundaries (pot lives in d_out; poisoned each run)
// =========================================================================
__global__ __launch_bounds__(256) void init_pot_kernel(
    const float* __restrict__ b2, const float* __restrict__ lb,
    const float* __restrict__ rb, float* __restrict__ pot)
{
    const int idx = blockIdx.x * 256 + threadIdx.x;
    if (idx < M_ * C_) {
        const int c = idx % C_;
        const int t = (idx / C_) & (S_ - 1);
        float v = b2[c];
        if (t == 0)      v += lb[c];
        if (t == S_ - 1) v += rb[c];
        pot[idx] = v;
    }
}

// =========================================================================
// Kernel 2a: W1 [k][n] fp32 -> w1t [n][k] bf16 (LDS-tiled transpose)
// =========================================================================
__global__ __launch_bounds__(256) void prep_w1_kernel(
    const float* __restrict__ W1, unsigned short* __restrict__ w1t)
{
    __shared__ float t[32][33];
    const int bx = blockIdx.x;            // n tile (24)
    const int by = blockIdx.y;            // k tile (24)
    const int lx = threadIdx.x & 31, ly = threadIdx.x >> 5;   // 32 x 8
    #pragma unroll
    for (int j = 0; j < 4; ++j)
        t[ly + 8 * j][lx] = W1[(by * 32 + ly + 8 * j) * H_ + bx * 32 + lx];
    __syncthreads();
    #pragma unroll
    for (int j = 0; j < 4; ++j)
        w1t[(size_t)(bx * 32 + ly + 8 * j) * D_ + by * 32 + lx] = f2bf(t[lx][ly + 8 * j]);
}

// =========================================================================
// Kernel 2b: X fp32 -> bf16 (elementwise, memory-bound)
// =========================================================================
__global__ __launch_bounds__(256) void prep_x_kernel(
    const float* __restrict__ X, unsigned short* __restrict__ xbf)
{
    const size_t i0 = ((size_t)blockIdx.x * 256 + threadIdx.x) * 8;
    const float4 a = *(const float4*)(X + i0);
    const float4 b = *(const float4*)(X + i0 + 4);
    union { unsigned short u[8]; uint4 v; } o;
    o.u[0] = f2bf(a.x); o.u[1] = f2bf(a.y); o.u[2] = f2bf(a.z); o.u[3] = f2bf(a.w);
    o.u[4] = f2bf(b.x); o.u[5] = f2bf(b.y); o.u[6] = f2bf(b.z); o.u[7] = f2bf(b.w);
    *(uint4*)(xbf + i0) = o.v;
}

// =========================================================================
// Kernel 2c: REGISTER-DIRECT MFMA GEMM — no LDS staging, no K-loop barriers.
// R4-R6 proved the barriered LDS K-loop plateaus at ~105 us (MfmaUtil 10-15%)
// regardless of buffering/occupancy: every variant stalls collectively at
// __syncthreads+drain. Here each wave loads its own fragments global->reg
// (B is L2-resident 1.18 MB; A bf16 L3/XCD-L2), pipelined 1 K-step ahead;
// the compiler emits MFMA<->global_load interleave with fine vmcnt — the
// AITER pattern, expressible only because the K-loop has no sync points.
// Wave tile 64x64: 16 MFMA : 8 x dwordx4 loads per K-step.
// =========================================================================
__global__ __launch_bounds__(256) void gemm_reg_kernel(
    const unsigned short* __restrict__ xbf,   // [M_, D_] bf16
    const unsigned short* __restrict__ w1t,   // [H_, D_] bf16 (n-major)
    const float* __restrict__ b1,
    const float* __restrict__ W2,             // [H_, C_]
    float* __restrict__ pot)                  // [M_, C_] pre-initialized
{
    __shared__ float pp[2][128][C_];          // 5 KB (epilogue only)

    const int tid  = threadIdx.x;
    const int lane = tid & 63, w = tid >> 6;
    const int wm   = w >> 1, wn = w & 1;
    const int i15  = lane & 15, quad = lane >> 4;

    // XCD swizzle: 6 n-blocks of an m-tile land on the same XCD (bid%8)
    const int bid = blockIdx.x;
    const int r8 = bid & 7, q8 = bid >> 3;
    const int nb = q8 % 6, mhi = q8 / 6;
    const int m0 = (mhi * 8 + r8) * 128;
    const int n0 = nb * 128;

    // per-fragment global pointers (advance 32 elements = 64 B per K-step)
    const unsigned short* pa[4];
    const unsigned short* pb[4];
    #pragma unroll
    for (int mi = 0; mi < 4; ++mi)
        pa[mi] = xbf + (size_t)(m0 + wm * 64 + mi * 16 + i15) * D_ + quad * 8;
    #pragma unroll
    for (int ni = 0; ni < 4; ++ni)
        pb[ni] = w1t + (size_t)(n0 + wn * 64 + ni * 16 + i15) * D_ + quad * 8;

    f32x4 acc[4][4];
    #pragma unroll
    for (int mi = 0; mi < 4; ++mi)
        #pragma unroll
        for (int ni = 0; ni < 4; ++ni)
            acc[mi][ni] = (f32x4){0.f, 0.f, 0.f, 0.f};

    // prologue: K-step 0 fragments
    short8 a_cur[4], b_cur[4];
    #pragma unroll
    for (int mi = 0; mi < 4; ++mi) a_cur[mi] = *(const short8*)pa[mi];
    #pragma unroll
    for (int ni = 0; ni < 4; ++ni) b_cur[ni] = *(const short8*)pb[ni];

    #define KITERS (D_ / 32)
    for (int kt = 0; kt < KITERS; ++kt) {
        short8 a_nxt[4], b_nxt[4];
        if (kt + 1 < KITERS) {
            // issue next K-step's loads; they stay in flight during the MFMAs
            #pragma unroll
            for (int mi = 0; mi < 4; ++mi) { pa[mi] += 32; a_nxt[mi] = *(const short8*)pa[mi]; }
            #pragma unroll
            for (int ni = 0; ni < 4; ++ni) { pb[ni] += 32; b_nxt[ni] = *(const short8*)pb[ni]; }
        }

        #pragma unroll
        for (int ni = 0; ni < 4; ++ni)
            #pragma unroll
            for (int mi = 0; mi < 4; ++mi)
                acc[mi][ni] = __builtin_amdgcn_mfma_f32_16x16x32_bf16(
                    a_cur[mi], b_cur[ni], acc[mi][ni], 0, 0, 0);

        if (kt + 1 < KITERS) {
            #pragma unroll
            for (int mi = 0; mi < 4; ++mi) a_cur[mi] = a_nxt[mi];
            #pragma unroll
            for (int ni = 0; ni < 4; ++ni) b_cur[ni] = b_nxt[ni];
        }
    }

    // ---- epilogue: relu(h+b1)@W2, wave-partial -> LDS -> block atomics ----
    // (verbatim from verified R5 kernel)
    float b1v[4], w2v[4][C_];
    #pragma unroll
    for (int ni = 0; ni < 4; ++ni) {
        const int col = n0 + wn * 64 + ni * 16 + i15;
        b1v[ni] = b1[col];
        #pragma unroll
        for (int cc = 0; cc < C_; ++cc) w2v[ni][cc] = W2[col * C_ + cc];
    }

    #pragma unroll
    for (int mi = 0; mi < 4; ++mi) {
        float ps[4][C_];
        #pragma unroll
        for (int r = 0; r < 4; ++r)
            #pragma unroll
            for (int cc = 0; cc < C_; ++cc) ps[r][cc] = 0.f;

        #pragma unroll
        for (int ni = 0; ni < 4; ++ni)
            #pragma unroll
            for (int r = 0; r < 4; ++r) {
                float h = acc[mi][ni][r] + b1v[ni];
                h = h > 0.f ? h : 0.f;
                #pragma unroll
                for (int cc = 0; cc < C_; ++cc)
                    ps[r][cc] = fmaf(h, w2v[ni][cc], ps[r][cc]);
            }

        #pragma unroll
        for (int off = 1; off < 16; off <<= 1)
            #pragma unroll
            for (int r = 0; r < 4; ++r)
                #pragma unroll
                for (int cc = 0; cc < C_; ++cc)
                    ps[r][cc] += __shfl_xor(ps[r][cc], off, 64);

        if (i15 == 0) {
            #pragma unroll
            for (int r = 0; r < 4; ++r) {
                const int row = wm * 64 + mi * 16 + quad * 4 + r;
                #pragma unroll
                for (int cc = 0; cc < C_; ++cc)
                    pp[wn][row][cc] = ps[r][cc];
            }
        }
    }
    __syncthreads();

    for (int idx = tid; idx < 128 * C_; idx += 256) {
        const int row = idx / C_, cc = idx % C_;
        atomicAdd(&pot[(size_t)(m0 + row) * C_ + cc],
                  pp[0][row][cc] + pp[1][row][cc]);
    }
}

// =========================================================================
// Mid fallback (R3 kernel, proven 162 us): bf16 B from ws, fp32 A via LDS
// =========================================================================
__device__ __forceinline__ void gload16(const void* g, void* l) {
    __builtin_amdgcn_global_load_lds(
        (const __attribute__((address_space(1))) unsigned int*)g,
        (__attribute__((address_space(3))) unsigned int*)l, 16, 0, 0);
}

__global__ __launch_bounds__(256) void gemm_bf16_kernel(
    const float* __restrict__ X,
    const unsigned short* __restrict__ w1t,
    const float* __restrict__ b1,
    const float* __restrict__ W2,
    float* __restrict__ pot)
{
    __shared__ __align__(16) float          Asm[128 * 32];
    __shared__ __align__(16) unsigned short Bsm[128 * 32];
    __shared__ float pp[2][128][C_];

    const int tid  = threadIdx.x;
    const int lane = tid & 63, w = tid >> 6;
    const int wm   = w >> 1, wn = w & 1;
    const int i15  = lane & 15, quad = lane >> 4;

    const int bid = blockIdx.x;
    const int r8 = bid & 7, q8 = bid >> 3;
    const int nb = q8 % 6, mhi = q8 / 6;
    const int m0 = (mhi * 8 + r8) * 128;
    const int n0 = nb * 128;

    const float* gA[4];
    float* lA[4];
    const unsigned short* gB[2];
    unsigned short* lB[2];
    #pragma unroll
    for (int i = 0; i < 4; ++i) {
        const int a = 4 * w + i, g = a >> 1, h = a & 1;
        gA[i] = X + (size_t)(m0 + g * 16 + i15) * D_ + (4 * h + quad) * 4;
        lA[i] = &Asm[g * 512 + h * 256];
    }
    #pragma unroll
    for (int i = 0; i < 2; ++i) {
        const int b = 2 * w + i;
        gB[i] = w1t + (size_t)(n0 + b * 16 + i15) * D_ + quad * 8;
        lB[i] = &Bsm[b * 512];
    }

    f32x4 acc[4][4];
    #pragma unroll
    for (int mi = 0; mi < 4; ++mi)
        #pragma unroll
        for (int ni = 0; ni < 4; ++ni)
            acc[mi][ni] = (f32x4){0.f, 0.f, 0.f, 0.f};

    for (int kt = 0; kt < D_ / 32; ++kt) {
        __syncthreads();
        #pragma unroll
        for (int i = 0; i < 4; ++i) { gload16(gA[i], lA[i]); gA[i] += 32; }
        #pragma unroll
        for (int i = 0; i < 2; ++i) { gload16(gB[i], lB[i]); gB[i] += 32; }
        __syncthreads();

        short8 af[4];
        #pragma unroll
        for (int mi = 0; mi < 4; ++mi) {
            const int row = wm * 64 + mi * 16 + i15;
            const int base = (row >> 4) * 512 + (row & 15) * 4 + quad * 128;
            const f32x4 lo = *(const f32x4*)&Asm[base];
            const f32x4 hi = *(const f32x4*)&Asm[base + 64];
            float f[8];
            *(f32x4*)&f[0] = lo; *(f32x4*)&f[4] = hi;
            union { short8 s; unsigned short u[8]; } cv;
            #pragma unroll
            for (int j = 0; j < 8; ++j) cv.u[j] = f2bf(f[j]);
            af[mi] = cv.s;
        }
        short8 bfr[4];
        #pragma unroll
        for (int ni = 0; ni < 4; ++ni) {
            const int row = wn * 64 + ni * 16 + i15;
            bfr[ni] = *(const short8*)&Bsm[(row >> 4) * 512 + quad * 128 + (row & 15) * 8];
        }
        #pragma unroll
        for (int ni = 0; ni < 4; ++ni)
            #pragma unroll
            for (int mi = 0; mi < 4; ++mi)
                acc[mi][ni] = __builtin_amdgcn_mfma_f32_16x16x32_bf16(
                    af[mi], bfr[ni], acc[mi][ni], 0, 0, 0);
    }

    float b1v[4], w2v[4][C_];
    #pragma unroll
    for (int ni = 0; ni < 4; ++ni) {
        const int col = n0 + wn * 64 + ni * 16 + i15;
        b1v[ni] = b1[col];
        #pragma unroll
        for (int cc = 0; cc < C_; ++cc) w2v[ni][cc] = W2[col * C_ + cc];
    }

    #pragma unroll
    for (int mi = 0; mi < 4; ++mi) {
        float ps[4][C_];
        #pragma unroll
        for (int r = 0; r < 4; ++r)
            #pragma unroll
            for (int cc = 0; cc < C_; ++cc) ps[r][cc] = 0.f;

        #pragma unroll
        for (int ni = 0; ni < 4; ++ni)
            #pragma unroll
            for (int r = 0; r < 4; ++r) {
                float h = acc[mi][ni][r] + b1v[ni];
                h = h > 0.f ? h : 0.f;
                #pragma unroll
                for (int cc = 0; cc < C_; ++cc)
                    ps[r][cc] = fmaf(h, w2v[ni][cc], ps[r][cc]);
            }

        #pragma unroll
        for (int off = 1; off < 16; off <<= 1)
            #pragma unroll
            for (int r = 0; r < 4; ++r)
                #pragma unroll
                for (int cc = 0; cc < C_; ++cc)
                    ps[r][cc] += __shfl_xor(ps[r][cc], off, 64);

        if (i15 == 0) {
            #pragma unroll
            for (int r = 0; r < 4; ++r) {
                const int row = wm * 64 + mi * 16 + quad * 4 + r;
                #pragma unroll
                for (int cc = 0; cc < C_; ++cc)
                    pp[wn][row][cc] = ps[r][cc];
            }
        }
    }
    __syncthreads();

    for (int idx = tid; idx < 128 * C_; idx += 256) {
        const int row = idx / C_, cc = idx % C_;
        atomicAdd(&pot[(size_t)(m0 + row) * C_ + cc],
                  pp[0][row][cc] + pp[1][row][cc]);
    }
}

// =========================================================================
// Last-resort fp32 GEMM (R1 kernel, proven) if ws < 1.18 MB
// =========================================================================
#define FBK 8
#define FLDS 132
__global__ __launch_bounds__(256) void gemm_relu_pot_kernel(
    const float* __restrict__ X, const float* __restrict__ W1,
    const float* __restrict__ b1, const float* __restrict__ W2,
    float* __restrict__ pot)
{
    __shared__ float As[FBK * FLDS];
    __shared__ float Bs[FBK * FLDS];
    __shared__ float w2s[128][C_];

    const int tid = threadIdx.x;
    const int tx = tid & 15, ty = tid >> 4;
    const int m0 = blockIdx.y * 128, n0 = blockIdx.x * 128;

    for (int idx = tid; idx < 128 * C_; idx += 256)
        w2s[idx / C_][idx % C_] = W2[(n0 + idx / C_) * C_ + idx % C_];

    float acc[2][2][4][4];
    #pragma unroll
    for (int a = 0; a < 2; ++a)
        #pragma unroll
        for (int b = 0; b < 2; ++b)
            #pragma unroll
            for (int i = 0; i < 4; ++i)
                #pragma unroll
                for (int j = 0; j < 4; ++j) acc[a][b][i][j] = 0.f;

    const int arow = tid >> 1, aq = tid & 1;
    const int brow = tid >> 5, bq = tid & 31;
    const float* Aptr = X + (m0 + arow) * D_ + aq * 4;
    const float* Bptr = W1 + brow * H_ + n0 + bq * 4;

    for (int kt = 0; kt < D_; kt += FBK) {
        const float4 avv = *(const float4*)Aptr;
        const float4 bvv = *(const float4*)Bptr;
        __syncthreads();
        As[(aq * 4 + 0) * FLDS + arow] = avv.x;
        As[(aq * 4 + 1) * FLDS + arow] = avv.y;
        As[(aq * 4 + 2) * FLDS + arow] = avv.z;
        As[(aq * 4 + 3) * FLDS + arow] = avv.w;
        *(float4*)&Bs[brow * FLDS + bq * 4] = bvv;
        __syncthreads();
        #pragma unroll
        for (int k = 0; k < FBK; ++k) {
            const float4 a0 = *(const float4*)&As[k * FLDS + (ty << 2)];
            const float4 a1 = *(const float4*)&As[k * FLDS + 64 + (ty << 2)];
            const float4 b0 = *(const float4*)&Bs[k * FLDS + (tx << 2)];
            const float4 b1r = *(const float4*)&Bs[k * FLDS + 64 + (tx << 2)];
            const float ar[2][4] = {{a0.x,a0.y,a0.z,a0.w},{a1.x,a1.y,a1.z,a1.w}};
            const float br[2][4] = {{b0.x,b0.y,b0.z,b0.w},{b1r.x,b1r.y,b1r.z,b1r.w}};
            #pragma unroll
            for (int ri = 0; ri < 2; ++ri)
                #pragma unroll
                for (int i = 0; i < 4; ++i)
                    #pragma unroll
                    for (int rj = 0; rj < 2; ++rj)
                        #pragma unroll
                        for (int j = 0; j < 4; ++j)
                            acc[ri][rj][i][j] = fmaf(ar[ri][i], br[rj][j], acc[ri][rj][i][j]);
        }
        Aptr += FBK;
        Bptr += FBK * H_;
    }

    float ps[2][4][C_];
    #pragma unroll
    for (int ri = 0; ri < 2; ++ri)
        #pragma unroll
        for (int i = 0; i < 4; ++i)
            #pragma unroll
            for (int cc = 0; cc < C_; ++cc) ps[ri][i][cc] = 0.f;

    #pragma unroll
    for (int rj = 0; rj < 2; ++rj)
        #pragma unroll
        for (int j = 0; j < 4; ++j) {
            const int nl = rj * 64 + (tx << 2) + j;
            const float bj = b1[n0 + nl];
            float w2c[C_];
            #pragma unroll
            for (int cc = 0; cc < C_; ++cc) w2c[cc] = w2s[nl][cc];
            #pragma unroll
            for (int ri = 0; ri < 2; ++ri)
                #pragma unroll
                for (int i = 0; i < 4; ++i) {
                    float h = acc[ri][rj][i][j] + bj;
                    h = h > 0.f ? h : 0.f;
                    #pragma unroll
                    for (int cc = 0; cc < C_; ++cc)
                        ps[ri][i][cc] = fmaf(h, w2c[cc], ps[ri][i][cc]);
                }
        }

    #pragma unroll
    for (int off = 1; off < 16; off <<= 1)
        #pragma unroll
        for (int ri = 0; ri < 2; ++ri)
            #pragma unroll
            for (int i = 0; i < 4; ++i)
                #pragma unroll
                for (int cc = 0; cc < C_; ++cc)
                    ps[ri][i][cc] += __shfl_xor(ps[ri][i][cc], off, 64);

    if (tx == 0)
        #pragma unroll
        for (int ri = 0; ri < 2; ++ri)
            #pragma unroll
            for (int i = 0; i < 4; ++i) {
                const int m = m0 + ri * 64 + (ty << 2) + i;
                #pragma unroll
                for (int cc = 0; cc < C_; ++cc)
                    atomicAdd(&pot[m * C_ + cc], ps[ri][i][cc]);
            }
}

// =========================================================================
// Kernel 3: Viterbi via max-plus associative scan (R4-R6, verified).
// =========================================================================
__global__ __launch_bounds__(64) void viterbi_kernel(
    const float* __restrict__ pot, const float* __restrict__ trans,
    const int* __restrict__ mask, float* __restrict__ decoded,
    float* __restrict__ seqlen, float* __restrict__ chain_out)
{
    const int b = blockIdx.x;
    const int lane = threadIdx.x;

    __shared__ float pl[S_ * C_];
    __shared__ unsigned int bpk[S_];
    __shared__ unsigned int gseg[64];
    __shared__ int bt[64];
    __shared__ int dec_s[S_];
    __shared__ int s_last;

    const float* pb = pot + b * (S_ * C_);
    for (int i = lane; i < S_ * C_; i += 64) pl[i] = pb[i];

    int mcnt = 0;
    const int* mb = mask + b * S_;
    for (int i = lane; i < S_; i += 64) mcnt += (mb[i] != 0) ? 1 : 0;
    #pragma unroll
    for (int off = 32; off >= 1; off >>= 1) mcnt += __shfl_xor(mcnt, off, 64);

    if (b == 0 && lane < C_ * C_) chain_out[lane] = trans[lane];

    float tr[C_][C_];
    #pragma unroll
    for (int p = 0; p < C_; ++p)
        #pragma unroll
        for (int c = 0; c < C_; ++c) tr[p][c] = trans[p * C_ + c];

    __syncthreads();

    const float NEG = -1.0e30f;

    float G[C_][C_];
    #pragma unroll
    for (int c = 0; c < C_; ++c)
        #pragma unroll
        for (int p = 0; p < C_; ++p) G[c][p] = (c == p) ? 0.f : NEG;

    for (int j = 1; j <= 8; ++j) {
        const int t = 8 * lane + j;
        if (t < S_) {
            float ng[C_][C_];
            #pragma unroll
            for (int c = 0; c < C_; ++c) {
                const float pc = pl[t * C_ + c];
                #pragma unroll
                for (int p = 0; p < C_; ++p) {
                    float m = tr[0][c] + G[0][p];
                    #pragma unroll
                    for (int q = 1; q < C_; ++q)
                        m = fmaxf(m, tr[q][c] + G[q][p]);
                    ng[c][p] = m + pc;
                }
            }
            #pragma unroll
            for (int c = 0; c < C_; ++c)
                #pragma unroll
                for (int p = 0; p < C_; ++p) G[c][p] = ng[c][p];
        }
    }

    #pragma unroll
    for (int d = 1; d < 64; d <<= 1) {
        float Q[C_][C_];
        #pragma unroll
        for (int q = 0; q < C_; ++q)
            #pragma unroll
            for (int p = 0; p < C_; ++p) Q[q][p] = __shfl_up(G[q][p], d, 64);
        if (lane >= d) {
            float ng[C_][C_];
            #pragma unroll
            for (int c = 0; c < C_; ++c)
                #pragma unroll
                for (int p = 0; p < C_; ++p) {
                    float m = G[c][0] + Q[0][p];
                    #pragma unroll
                    for (int q = 1; q < C_; ++q)
                        m = fmaxf(m, G[c][q] + Q[q][p]);
                    ng[c][p] = m;
                }
            #pragma unroll
            for (int c = 0; c < C_; ++c)
                #pragma unroll
                for (int p = 0; p < C_; ++p) G[c][p] = ng[c][p];
        }
    }

    float a[C_];
    {
        float E[C_][C_];
        #pragma unroll
        for (int c = 0; c < C_; ++c)
            #pragma unroll
            for (int p = 0; p < C_; ++p) E[c][p] = __shfl_up(G[c][p], 1, 64);
        float a0[C_];
        #pragma unroll
        for (int c = 0; c < C_; ++c) a0[c] = pl[c];
        if (lane == 0) {
            #pragma unroll
            for (int c = 0; c < C_; ++c) a[c] = a0[c];
        } else {
            #pragma unroll
            for (int c = 0; c < C_; ++c) {
                float m = E[c][0] + a0[0];
                #pragma unroll
                for (int q = 1; q < C_; ++q) m = fmaxf(m, E[c][q] + a0[q]);
                a[c] = m;
            }
        }
    }

    for (int j = 1; j <= 8; ++j) {
        const int t = 8 * lane + j;
        if (t < S_) {
            unsigned int mpack = 0;
            float na[C_];
            #pragma unroll
            for (int c = 0; c < C_; ++c) {
                float best = a[0] + tr[0][c];
                int arg = 0;
                #pragma unroll
                for (int p = 1; p < C_; ++p) {
                    const float s = a[p] + tr[p][c];
                    if (s > best) { best = s; arg = p; }
                }
                mpack |= (unsigned int)arg << (3 * c);
                na[c] = best + pl[t * C_ + c];
            }
            bpk[t] = mpack;
            #pragma unroll
            for (int c = 0; c < C_; ++c) a[c] = na[c];
        }
    }

    if (lane == 63) {
        float best = a[0];
        int arg = 0;
        #pragma unroll
        for (int p = 1; p < C_; ++p)
            if (a[p] > best) { best = a[p]; arg = p; }
        s_last = arg;
    }
    if (lane == 0) bpk[0] = 0;
    __syncthreads();

    const int last = s_last;

    unsigned int g = 0u | (1u << 3) | (2u << 6) | (3u << 9) | (4u << 12);
    #pragma unroll
    for (int j = 7; j >= 0; --j) {
        const int t = 8 * lane + j;
        if (t >= 1) {
            const unsigned int m = bpk[t];
            unsigned int ng = 0;
            #pragma unroll
            for (int x = 0; x < C_; ++x) {
                const unsigned int gx = (g >> (3 * x)) & 7u;
                ng |= ((m >> (3 * gx)) & 7u) << (3 * x);
            }
            g = ng;
        }
    }
    gseg[lane] = g;
    __syncthreads();

    if (lane == 0) {
        int cur = last;
        for (int l = 63; l >= 0; --l) {
            bt[l] = cur;
            cur = (int)((gseg[l] >> (3 * cur)) & 7u);
        }
        seqlen[b] = (float)mcnt;
    }
    __syncthreads();

    {
        int tag = bt[lane];
        const int t0 = 8 * lane;
        dec_s[t0 + 7] = tag;
        #pragma unroll
        for (int t = t0 + 7; t >= t0 + 1; --t) {
            tag = (int)((bpk[t] >> (3 * tag)) & 7u);
            dec_s[t - 1] = tag;
        }
    }
    __syncthreads();

    float* db = decoded + b * S_;
    for (int i = lane; i < S_; i += 64) db[i] = (float)dec_s[i];
}

// =========================================================================
extern "C" void kernel_launch(void* const* d_in, const int* in_sizes, int n_in,
                              void* d_out, int out_size, void* d_ws, size_t ws_size,
                              hipStream_t stream) {
    const float* hs    = (const float*)d_in[0];
    const int*   mask  = (const int*)  d_in[1];
    const float* W1    = (const float*)d_in[2];
    const float* b1    = (const float*)d_in[3];
    const float* W2    = (const float*)d_in[4];
    const float* b2    = (const float*)d_in[5];
    const float* chain = (const float*)d_in[6];
    const float* lb    = (const float*)d_in[7];
    const float* rb    = (const float*)d_in[8];

    float* out      = (float*)d_out;
    float* decoded  = out;
    float* pot      = out + M_;
    float* seq      = out + M_ + M_ * C_;
    float* chainout = seq + B_;

    init_pot_kernel<<<(M_ * C_ + 255) / 256, 256, 0, stream>>>(b2, lb, rb, pot);

    const size_t need_w1 = (size_t)W1T_ELEMS * sizeof(unsigned short);            // 1.18 MB
    const size_t need_all = need_w1 + (size_t)XBF_ELEMS * sizeof(unsigned short); // 51.5 MB

    if (ws_size >= need_all) {
        unsigned short* w1t = (unsigned short*)d_ws;
        unsigned short* xbf = w1t + W1T_ELEMS;
        dim3 pgrid(H_ / 32, D_ / 32);
        prep_w1_kernel<<<pgrid, 256, 0, stream>>>(W1, w1t);
        prep_x_kernel<<<XBF_ELEMS / (256 * 8), 256, 0, stream>>>(hs, xbf);
        gemm_reg_kernel<<<1536, 256, 0, stream>>>(xbf, w1t, b1, W2, pot);
    } else if (ws_size >= need_w1) {
        unsigned short* w1t = (unsigned short*)d_ws;
        dim3 pgrid(H_ / 32, D_ / 32);
        prep_w1_kernel<<<pgrid, 256, 0, stream>>>(W1, w1t);
        gemm_bf16_kernel<<<1536, 256, 0, stream>>>(hs, w1t, b1, W2, pot);
    } else {
        dim3 grid(H_ / 128, M_ / 128);
        gemm_relu_pot_kernel<<<grid, 256, 0, stream>>>(hs, W1, b1, W2, pot);
    }

    viterbi_kernel<<<B_, 64, 0, stream>>>(pot, chain, mask, decoded, seq, chainout);
}

// Round 8
// 272.902 us; speedup vs baseline: 1.1837x; 1.1837x over previous
//
#include <hip/hip_runtime.h>

// Problem constants
#define B_  64
#define S_  512
#define D_  768
#define H_  768
#define C_  5
#define M_  (B_ * S_)        // 32768 rows

typedef float f32x4 __attribute__((ext_vector_type(4)));
typedef short short8 __attribute__((ext_vector_type(8)));   // bf16x8 MFMA operand

#define W1T_ELEMS (D_ * H_)      // 589824  (bf16: 1.18 MB)
#define XBF_ELEMS (M_ * D_)      // 25165824 (bf16: 50.33 MB)

// prep_all grid partition
#define PX_BLOCKS   (XBF_ELEMS / (256 * 8))          // 12288
#define PW_BLOCKS   ((D_ / 32) * (H_ / 32))          // 576
#define PI_BLOCKS   ((M_ * C_ + 255) / 256)          // 640

__device__ __forceinline__ unsigned short f2bf(float f) {
    unsigned int u = __float_as_uint(f);
    u += 0x7FFFu + ((u >> 16) & 1u);     // RNE
    return (unsigned short)(u >> 16);
}

// =========================================================================
// Kernel 1: fused prep — prep_x | prep_w1 | init_pot in one dispatch
// (branch is block-uniform; saves 2 launch overheads)
// =========================================================================
__global__ __launch_bounds__(256) void prep_all_kernel(
    const float* __restrict__ X, const float* __restrict__ W1,
    const float* __restrict__ b2, const float* __restrict__ lb,
    const float* __restrict__ rb,
    unsigned short* __restrict__ xbf, unsigned short* __restrict__ w1t,
    float* __restrict__ pot)
{
    __shared__ float t[32][33];
    const int bid = blockIdx.x;
    const int tid = threadIdx.x;

    if (bid < PX_BLOCKS) {
        // ---- X fp32 -> bf16 ----
        const size_t i0 = ((size_t)bid * 256 + tid) * 8;
        const float4 a = *(const float4*)(X + i0);
        const float4 b = *(const float4*)(X + i0 + 4);
        union { unsigned short u[8]; uint4 v; } o;
        o.u[0] = f2bf(a.x); o.u[1] = f2bf(a.y); o.u[2] = f2bf(a.z); o.u[3] = f2bf(a.w);
        o.u[4] = f2bf(b.x); o.u[5] = f2bf(b.y); o.u[6] = f2bf(b.z); o.u[7] = f2bf(b.w);
        *(uint4*)(xbf + i0) = o.v;
    } else if (bid < PX_BLOCKS + PW_BLOCKS) {
        // ---- W1 [k][n] fp32 -> w1t [n][k] bf16 (LDS-tiled transpose) ----
        const int b2i = bid - PX_BLOCKS;
        const int bx = b2i % (H_ / 32);       // n tile
        const int by = b2i / (H_ / 32);       // k tile
        const int lx = tid & 31, ly = tid >> 5;
        #pragma unroll
        for (int j = 0; j < 4; ++j)
            t[ly + 8 * j][lx] = W1[(by * 32 + ly + 8 * j) * H_ + bx * 32 + lx];
        __syncthreads();
        #pragma unroll
        for (int j = 0; j < 4; ++j)
            w1t[(size_t)(bx * 32 + ly + 8 * j) * D_ + by * 32 + lx] = f2bf(t[lx][ly + 8 * j]);
    } else {
        // ---- pot = b2 + boundaries ----
        const int idx = (bid - PX_BLOCKS - PW_BLOCKS) * 256 + tid;
        if (idx < M_ * C_) {
            const int c = idx % C_;
            const int tt = (idx / C_) & (S_ - 1);
            float v = b2[c];
            if (tt == 0)      v += lb[c];
            if (tt == S_ - 1) v += rb[c];
            pot[idx] = v;
        }
    }
}

// standalone prep_w1 for the fallback branch only
__global__ __launch_bounds__(256) void prep_w1_kernel(
    const float* __restrict__ W1, unsigned short* __restrict__ w1t)
{
    __shared__ float t[32][33];
    const int bx = blockIdx.x, by = blockIdx.y;
    const int lx = threadIdx.x & 31, ly = threadIdx.x >> 5;
    #pragma unroll
    for (int j = 0; j < 4; ++j)
        t[ly + 8 * j][lx] = W1[(by * 32 + ly + 8 * j) * H_ + bx * 32 + lx];
    __syncthreads();
    #pragma unroll
    for (int j = 0; j < 4; ++j)
        w1t[(size_t)(bx * 32 + ly + 8 * j) * D_ + by * 32 + lx] = f2bf(t[lx][ly + 8 * j]);
}

__global__ __launch_bounds__(256) void init_pot_kernel(
    const float* __restrict__ b2, const float* __restrict__ lb,
    const float* __restrict__ rb, float* __restrict__ pot)
{
    const int idx = blockIdx.x * 256 + threadIdx.x;
    if (idx < M_ * C_) {
        const int c = idx % C_;
        const int t = (idx / C_) & (S_ - 1);
        float v = b2[c];
        if (t == 0)      v += lb[c];
        if (t == S_ - 1) v += rb[c];
        pot[idx] = v;
    }
}

// =========================================================================
// Kernel 2: bf16 MFMA GEMM, BK=64, double-buffered, barrier every 64 K-elems.
// R5's BK=32 dbuf plateaued because __syncthreads' implicit vmcnt(0) always
// drains the freshest prefetch (depth can't help at barrier-per-iter cadence).
// BK=64 doubles the compute phase each prefetch ages through (32 MFMA +
// 16 ds_read ~450 cyc) AND halves barrier count: stall = max(0,L-C) shrinks
// on both factors. LDS = 64 KB exactly; epilogue pp aliases Asm[0].
// =========================================================================
__device__ __forceinline__ void gload16(const void* g, void* l) {
    __builtin_amdgcn_global_load_lds(
        (const __attribute__((address_space(1))) unsigned int*)g,
        (__attribute__((address_space(3))) unsigned int*)l, 16, 0, 0);
}

__global__ __launch_bounds__(256) void gemm_bk64_kernel(
    const unsigned short* __restrict__ xbf,   // [M_, D_] bf16
    const unsigned short* __restrict__ w1t,   // [H_, D_] bf16 (n-major)
    const float* __restrict__ b1,
    const float* __restrict__ W2,             // [H_, C_]
    float* __restrict__ pot)                  // [M_, C_] pre-initialized
{
    // per buffer: 128 rows x 64 cols bf16 = 8192 shorts (two 4096-el chunks)
    __shared__ __align__(16) unsigned short Asm[2][8192];   // 32 KB
    __shared__ __align__(16) unsigned short Bsm[2][8192];   // 32 KB  (total 64 KB)

    const int tid  = threadIdx.x;
    const int lane = tid & 63, w = tid >> 6;
    const int wm   = w >> 1, wn = w & 1;
    const int i15  = lane & 15, quad = lane >> 4;

    // XCD swizzle: 6 n-blocks of an m-tile land on the same XCD (bid%8)
    const int bid = blockIdx.x;
    const int r8 = bid & 7, q8 = bid >> 3;
    const int nb = q8 % 6, mhi = q8 / 6;
    const int m0 = (mhi * 8 + r8) * 128;
    const int n0 = nb * 128;

    // staging: wave w owns row-groups {2w, 2w+1}; 2 chunks each => 4 A + 4 B
    const unsigned short* gA[2];
    const unsigned short* gB[2];
    int lofs[2];
    #pragma unroll
    for (int i = 0; i < 2; ++i) {
        const int g = 2 * w + i;
        gA[i] = xbf + (size_t)(m0 + g * 16 + i15) * D_ + quad * 8;
        gB[i] = w1t + (size_t)(n0 + g * 16 + i15) * D_ + quad * 8;
        lofs[i] = g * 512;
    }

    f32x4 acc[4][4];
    #pragma unroll
    for (int mi = 0; mi < 4; ++mi)
        #pragma unroll
        for (int ni = 0; ni < 4; ++ni)
            acc[mi][ni] = (f32x4){0.f, 0.f, 0.f, 0.f};

    // prologue: K-tile 0 (both 32-chunks) -> buf 0
    #pragma unroll
    for (int i = 0; i < 2; ++i) {
        gload16(gA[i],      &Asm[0][lofs[i]]);
        gload16(gA[i] + 32, &Asm[0][4096 + lofs[i]]);
        gload16(gB[i],      &Bsm[0][lofs[i]]);
        gload16(gB[i] + 32, &Bsm[0][4096 + lofs[i]]);
        gA[i] += 64; gB[i] += 64;
    }
    __syncthreads();

    #define KITERS (D_ / 64)    // 12
    for (int kt = 0; kt < KITERS; ++kt) {
        const int cur = kt & 1, nxt = cur ^ 1;

        // prefetch K-tile kt+1 (in flight during 32 MFMAs + 16 ds_reads)
        if (kt + 1 < KITERS) {
            #pragma unroll
            for (int i = 0; i < 2; ++i) {
                gload16(gA[i],      &Asm[nxt][lofs[i]]);
                gload16(gA[i] + 32, &Asm[nxt][4096 + lofs[i]]);
                gload16(gB[i],      &Bsm[nxt][lofs[i]]);
                gload16(gB[i] + 32, &Bsm[nxt][4096 + lofs[i]]);
                gA[i] += 64; gB[i] += 64;
            }
        }

        #pragma unroll
        for (int c = 0; c < 2; ++c) {
            const int cb = c * 4096;
            short8 af[4], bfr[4];
            #pragma unroll
            for (int mi = 0; mi < 4; ++mi)
                af[mi] = *(const short8*)&Asm[cur][cb + (wm * 4 + mi) * 512 + quad * 128 + i15 * 8];
            #pragma unroll
            for (int ni = 0; ni < 4; ++ni)
                bfr[ni] = *(const short8*)&Bsm[cur][cb + (wn * 4 + ni) * 512 + quad * 128 + i15 * 8];
            #pragma unroll
            for (int ni = 0; ni < 4; ++ni)
                #pragma unroll
                for (int mi = 0; mi < 4; ++mi)
                    acc[mi][ni] = __builtin_amdgcn_mfma_f32_16x16x32_bf16(
                        af[mi], bfr[ni], acc[mi][ni], 0, 0, 0);
        }

        __syncthreads();   // drains prefetch (aged a full 64-K compute phase)
    }

    // ---- epilogue: relu(h+b1)@W2, wave-partial -> LDS -> block atomics ----
    // pp aliases Asm[0] (all LDS reads completed at the final barrier above)
    float* pp = (float*)&Asm[0][0];          // [2][128][C_] = 5120 B

    float b1v[4], w2v[4][C_];
    #pragma unroll
    for (int ni = 0; ni < 4; ++ni) {
        const int col = n0 + wn * 64 + ni * 16 + i15;
        b1v[ni] = b1[col];
        #pragma unroll
        for (int cc = 0; cc < C_; ++cc) w2v[ni][cc] = W2[col * C_ + cc];
    }

    #pragma unroll
    for (int mi = 0; mi < 4; ++mi) {
        float ps[4][C_];
        #pragma unroll
        for (int r = 0; r < 4; ++r)
            #pragma unroll
            for (int cc = 0; cc < C_; ++cc) ps[r][cc] = 0.f;

        #pragma unroll
        for (int ni = 0; ni < 4; ++ni)
            #pragma unroll
            for (int r = 0; r < 4; ++r) {
                float h = acc[mi][ni][r] + b1v[ni];
                h = h > 0.f ? h : 0.f;
                #pragma unroll
                for (int cc = 0; cc < C_; ++cc)
                    ps[r][cc] = fmaf(h, w2v[ni][cc], ps[r][cc]);
            }

        #pragma unroll
        for (int off = 1; off < 16; off <<= 1)
            #pragma unroll
            for (int r = 0; r < 4; ++r)
                #pragma unroll
                for (int cc = 0; cc < C_; ++cc)
                    ps[r][cc] += __shfl_xor(ps[r][cc], off, 64);

        if (i15 == 0) {
            #pragma unroll
            for (int r = 0; r < 4; ++r) {
                const int row = wm * 64 + mi * 16 + quad * 4 + r;
                #pragma unroll
                for (int cc = 0; cc < C_; ++cc)
                    pp[(wn * 128 + row) * C_ + cc] = ps[r][cc];
            }
        }
    }
    __syncthreads();

    for (int idx = tid; idx < 128 * C_; idx += 256) {
        const int row = idx / C_, cc = idx % C_;
        atomicAdd(&pot[(size_t)(m0 + row) * C_ + cc],
                  pp[row * C_ + cc] + pp[(128 + row) * C_ + cc]);
    }
}

// =========================================================================
// Mid fallback (R3 kernel, proven): bf16 B from ws, fp32 A via LDS
// =========================================================================
__global__ __launch_bounds__(256) void gemm_bf16_kernel(
    const float* __restrict__ X,
    const unsigned short* __restrict__ w1t,
    const float* __restrict__ b1,
    const float* __restrict__ W2,
    float* __restrict__ pot)
{
    __shared__ __align__(16) float          Asm[128 * 32];
    __shared__ __align__(16) unsigned short Bsm[128 * 32];
    __shared__ float pp[2][128][C_];

    const int tid  = threadIdx.x;
    const int lane = tid & 63, w = tid >> 6;
    const int wm   = w >> 1, wn = w & 1;
    const int i15  = lane & 15, quad = lane >> 4;

    const int bid = blockIdx.x;
    const int r8 = bid & 7, q8 = bid >> 3;
    const int nb = q8 % 6, mhi = q8 / 6;
    const int m0 = (mhi * 8 + r8) * 128;
    const int n0 = nb * 128;

    const float* gA[4];
    float* lA[4];
    const unsigned short* gB[2];
    unsigned short* lB[2];
    #pragma unroll
    for (int i = 0; i < 4; ++i) {
        const int a = 4 * w + i, g = a >> 1, h = a & 1;
        gA[i] = X + (size_t)(m0 + g * 16 + i15) * D_ + (4 * h + quad) * 4;
        lA[i] = &Asm[g * 512 + h * 256];
    }
    #pragma unroll
    for (int i = 0; i < 2; ++i) {
        const int b = 2 * w + i;
        gB[i] = w1t + (size_t)(n0 + b * 16 + i15) * D_ + quad * 8;
        lB[i] = &Bsm[b * 512];
    }

    f32x4 acc[4][4];
    #pragma unroll
    for (int mi = 0; mi < 4; ++mi)
        #pragma unroll
        for (int ni = 0; ni < 4; ++ni)
            acc[mi][ni] = (f32x4){0.f, 0.f, 0.f, 0.f};

    for (int kt = 0; kt < D_ / 32; ++kt) {
        __syncthreads();
        #pragma unroll
        for (int i = 0; i < 4; ++i) { gload16(gA[i], lA[i]); gA[i] += 32; }
        #pragma unroll
        for (int i = 0; i < 2; ++i) { gload16(gB[i], lB[i]); gB[i] += 32; }
        __syncthreads();

        short8 af[4];
        #pragma unroll
        for (int mi = 0; mi < 4; ++mi) {
            const int row = wm * 64 + mi * 16 + i15;
            const int base = (row >> 4) * 512 + (row & 15) * 4 + quad * 128;
            const f32x4 lo = *(const f32x4*)&Asm[base];
            const f32x4 hi = *(const f32x4*)&Asm[base + 64];
            float f[8];
            *(f32x4*)&f[0] = lo; *(f32x4*)&f[4] = hi;
            union { short8 s; unsigned short u[8]; } cv;
            #pragma unroll
            for (int j = 0; j < 8; ++j) cv.u[j] = f2bf(f[j]);
            af[mi] = cv.s;
        }
        short8 bfr[4];
        #pragma unroll
        for (int ni = 0; ni < 4; ++ni) {
            const int row = wn * 64 + ni * 16 + i15;
            bfr[ni] = *(const short8*)&Bsm[(row >> 4) * 512 + quad * 128 + (row & 15) * 8];
        }
        #pragma unroll
        for (int ni = 0; ni < 4; ++ni)
            #pragma unroll
            for (int mi = 0; mi < 4; ++mi)
                acc[mi][ni] = __builtin_amdgcn_mfma_f32_16x16x32_bf16(
                    af[mi], bfr[ni], acc[mi][ni], 0, 0, 0);
    }

    float b1v[4], w2v[4][C_];
    #pragma unroll
    for (int ni = 0; ni < 4; ++ni) {
        const int col = n0 + wn * 64 + ni * 16 + i15;
        b1v[ni] = b1[col];
        #pragma unroll
        for (int cc = 0; cc < C_; ++cc) w2v[ni][cc] = W2[col * C_ + cc];
    }

    #pragma unroll
    for (int mi = 0; mi < 4; ++mi) {
        float ps[4][C_];
        #pragma unroll
        for (int r = 0; r < 4; ++r)
            #pragma unroll
            for (int cc = 0; cc < C_; ++cc) ps[r][cc] = 0.f;

        #pragma unroll
        for (int ni = 0; ni < 4; ++ni)
            #pragma unroll
            for (int r = 0; r < 4; ++r) {
                float h = acc[mi][ni][r] + b1v[ni];
                h = h > 0.f ? h : 0.f;
                #pragma unroll
                for (int cc = 0; cc < C_; ++cc)
                    ps[r][cc] = fmaf(h, w2v[ni][cc], ps[r][cc]);
            }

        #pragma unroll
        for (int off = 1; off < 16; off <<= 1)
            #pragma unroll
            for (int r = 0; r < 4; ++r)
                #pragma unroll
                for (int cc = 0; cc < C_; ++cc)
                    ps[r][cc] += __shfl_xor(ps[r][cc], off, 64);

        if (i15 == 0) {
            #pragma unroll
            for (int r = 0; r < 4; ++r) {
                const int row = wm * 64 + mi * 16 + quad * 4 + r;
                #pragma unroll
                for (int cc = 0; cc < C_; ++cc)
                    pp[wn][row][cc] = ps[r][cc];
            }
        }
    }
    __syncthreads();

    for (int idx = tid; idx < 128 * C_; idx += 256) {
        const int row = idx / C_, cc = idx % C_;
        atomicAdd(&pot[(size_t)(m0 + row) * C_ + cc],
                  pp[0][row][cc] + pp[1][row][cc]);
    }
}

// =========================================================================
// Last-resort fp32 GEMM (R1 kernel, proven) if ws < 1.18 MB
// =========================================================================
#define FBK 8
#define FLDS 132
__global__ __launch_bounds__(256) void gemm_relu_pot_kernel(
    const float* __restrict__ X, const float* __restrict__ W1,
    const float* __restrict__ b1, const float* __restrict__ W2,
    float* __restrict__ pot)
{
    __shared__ float As[FBK * FLDS];
    __shared__ float Bs[FBK * FLDS];
    __shared__ float w2s[128][C_];

    const int tid = threadIdx.x;
    const int tx = tid & 15, ty = tid >> 4;
    const int m0 = blockIdx.y * 128, n0 = blockIdx.x * 128;

    for (int idx = tid; idx < 128 * C_; idx += 256)
        w2s[idx / C_][idx % C_] = W2[(n0 + idx / C_) * C_ + idx % C_];

    float acc[2][2][4][4];
    #pragma unroll
    for (int a = 0; a < 2; ++a)
        #pragma unroll
        for (int b = 0; b < 2; ++b)
            #pragma unroll
            for (int i = 0; i < 4; ++i)
                #pragma unroll
                for (int j = 0; j < 4; ++j) acc[a][b][i][j] = 0.f;

    const int arow = tid >> 1, aq = tid & 1;
    const int brow = tid >> 5, bq = tid & 31;
    const float* Aptr = X + (m0 + arow) * D_ + aq * 4;
    const float* Bptr = W1 + brow * H_ + n0 + bq * 4;

    for (int kt = 0; kt < D_; kt += FBK) {
        const float4 avv = *(const float4*)Aptr;
        const float4 bvv = *(const float4*)Bptr;
        __syncthreads();
        As[(aq * 4 + 0) * FLDS + arow] = avv.x;
        As[(aq * 4 + 1) * FLDS + arow] = avv.y;
        As[(aq * 4 + 2) * FLDS + arow] = avv.z;
        As[(aq * 4 + 3) * FLDS + arow] = avv.w;
        *(float4*)&Bs[brow * FLDS + bq * 4] = bvv;
        __syncthreads();
        #pragma unroll
        for (int k = 0; k < FBK; ++k) {
            const float4 a0 = *(const float4*)&As[k * FLDS + (ty << 2)];
            const float4 a1 = *(const float4*)&As[k * FLDS + 64 + (ty << 2)];
            const float4 b0 = *(const float4*)&Bs[k * FLDS + (tx << 2)];
            const float4 b1r = *(const float4*)&Bs[k * FLDS + 64 + (tx << 2)];
            const float ar[2][4] = {{a0.x,a0.y,a0.z,a0.w},{a1.x,a1.y,a1.z,a1.w}};
            const float br[2][4] = {{b0.x,b0.y,b0.z,b0.w},{b1r.x,b1r.y,b1r.z,b1r.w}};
            #pragma unroll
            for (int ri = 0; ri < 2; ++ri)
                #pragma unroll
                for (int i = 0; i < 4; ++i)
                    #pragma unroll
                    for (int rj = 0; rj < 2; ++rj)
                        #pragma unroll
                        for (int j = 0; j < 4; ++j)
                            acc[ri][rj][i][j] = fmaf(ar[ri][i], br[rj][j], acc[ri][rj][i][j]);
        }
        Aptr += FBK;
        Bptr += FBK * H_;
    }

    float ps[2][4][C_];
    #pragma unroll
    for (int ri = 0; ri < 2; ++ri)
        #pragma unroll
        for (int i = 0; i < 4; ++i)
            #pragma unroll
            for (int cc = 0; cc < C_; ++cc) ps[ri][i][cc] = 0.f;

    #pragma unroll
    for (int rj = 0; rj < 2; ++rj)
        #pragma unroll
        for (int j = 0; j < 4; ++j) {
            const int nl = rj * 64 + (tx << 2) + j;
            const float bj = b1[n0 + nl];
            float w2c[C_];
            #pragma unroll
            for (int cc = 0; cc < C_; ++cc) w2c[cc] = w2s[nl][cc];
            #pragma unroll
            for (int ri = 0; ri < 2; ++ri)
                #pragma unroll
                for (int i = 0; i < 4; ++i) {
                    float h = acc[ri][rj][i][j] + bj;
                    h = h > 0.f ? h : 0.f;
                    #pragma unroll
                    for (int cc = 0; cc < C_; ++cc)
                        ps[ri][i][cc] = fmaf(h, w2c[cc], ps[ri][i][cc]);
                }
        }

    #pragma unroll
    for (int off = 1; off < 16; off <<= 1)
        #pragma unroll
        for (int ri = 0; ri < 2; ++ri)
            #pragma unroll
            for (int i = 0; i < 4; ++i)
                #pragma unroll
                for (int cc = 0; cc < C_; ++cc)
                    ps[ri][i][cc] += __shfl_xor(ps[ri][i][cc], off, 64);

    if (tx == 0)
        #pragma unroll
        for (int ri = 0; ri < 2; ++ri)
            #pragma unroll
            for (int i = 0; i < 4; ++i) {
                const int m = m0 + ri * 64 + (ty << 2) + i;
                #pragma unroll
                for (int cc = 0; cc < C_; ++cc)
                    atomicAdd(&pot[m * C_ + cc], ps[ri][i][cc]);
            }
}

// =========================================================================
// Kernel 3: Viterbi via max-plus associative scan (R4-R7, verified).
// =========================================================================
__global__ __launch_bounds__(64) void viterbi_kernel(
    const float* __restrict__ pot, const float* __restrict__ trans,
    const int* __restrict__ mask, float* __restrict__ decoded,
    float* __restrict__ seqlen, float* __restrict__ chain_out)
{
    const int b = blockIdx.x;
    const int lane = threadIdx.x;

    __shared__ float pl[S_ * C_];
    __shared__ unsigned int bpk[S_];
    __shared__ unsigned int gseg[64];
    __shared__ int bt[64];
    __shared__ int dec_s[S_];
    __shared__ int s_last;

    const float* pb = pot + b * (S_ * C_);
    for (int i = lane; i < S_ * C_; i += 64) pl[i] = pb[i];

    int mcnt = 0;
    const int* mb = mask + b * S_;
    for (int i = lane; i < S_; i += 64) mcnt += (mb[i] != 0) ? 1 : 0;
    #pragma unroll
    for (int off = 32; off >= 1; off >>= 1) mcnt += __shfl_xor(mcnt, off, 64);

    if (b == 0 && lane < C_ * C_) chain_out[lane] = trans[lane];

    float tr[C_][C_];
    #pragma unroll
    for (int p = 0; p < C_; ++p)
        #pragma unroll
        for (int c = 0; c < C_; ++c) tr[p][c] = trans[p * C_ + c];

    __syncthreads();

    const float NEG = -1.0e30f;

    float G[C_][C_];
    #pragma unroll
    for (int c = 0; c < C_; ++c)
        #pragma unroll
        for (int p = 0; p < C_; ++p) G[c][p] = (c == p) ? 0.f : NEG;

    for (int j = 1; j <= 8; ++j) {
        const int t = 8 * lane + j;
        if (t < S_) {
            float ng[C_][C_];
            #pragma unroll
            for (int c = 0; c < C_; ++c) {
                const float pc = pl[t * C_ + c];
                #pragma unroll
                for (int p = 0; p < C_; ++p) {
                    float m = tr[0][c] + G[0][p];
                    #pragma unroll
                    for (int q = 1; q < C_; ++q)
                        m = fmaxf(m, tr[q][c] + G[q][p]);
                    ng[c][p] = m + pc;
                }
            }
            #pragma unroll
            for (int c = 0; c < C_; ++c)
                #pragma unroll
                for (int p = 0; p < C_; ++p) G[c][p] = ng[c][p];
        }
    }

    #pragma unroll
    for (int d = 1; d < 64; d <<= 1) {
        float Q[C_][C_];
        #pragma unroll
        for (int q = 0; q < C_; ++q)
            #pragma unroll
            for (int p = 0; p < C_; ++p) Q[q][p] = __shfl_up(G[q][p], d, 64);
        if (lane >= d) {
            float ng[C_][C_];
            #pragma unroll
            for (int c = 0; c < C_; ++c)
                #pragma unroll
                for (int p = 0; p < C_; ++p) {
                    float m = G[c][0] + Q[0][p];
                    #pragma unroll
                    for (int q = 1; q < C_; ++q)
                        m = fmaxf(m, G[c][q] + Q[q][p]);
                    ng[c][p] = m;
                }
            #pragma unroll
            for (int c = 0; c < C_; ++c)
                #pragma unroll
                for (int p = 0; p < C_; ++p) G[c][p] = ng[c][p];
        }
    }

    float a[C_];
    {
        float E[C_][C_];
        #pragma unroll
        for (int c = 0; c < C_; ++c)
            #pragma unroll
            for (int p = 0; p < C_; ++p) E[c][p] = __shfl_up(G[c][p], 1, 64);
        float a0[C_];
        #pragma unroll
        for (int c = 0; c < C_; ++c) a0[c] = pl[c];
        if (lane == 0) {
            #pragma unroll
            for (int c = 0; c < C_; ++c) a[c] = a0[c];
        } else {
            #pragma unroll
            for (int c = 0; c < C_; ++c) {
                float m = E[c][0] + a0[0];
                #pragma unroll
                for (int q = 1; q < C_; ++q) m = fmaxf(m, E[c][q] + a0[q]);
                a[c] = m;
            }
        }
    }

    for (int j = 1; j <= 8; ++j) {
        const int t = 8 * lane + j;
        if (t < S_) {
            unsigned int mpack = 0;
            float na[C_];
            #pragma unroll
            for (int c = 0; c < C_; ++c) {
                float best = a[0] + tr[0][c];
                int arg = 0;
                #pragma unroll
                for (int p = 1; p < C_; ++p) {
                    const float s = a[p] + tr[p][c];
                    if (s > best) { best = s; arg = p; }
                }
                mpack |= (unsigned int)arg << (3 * c);
                na[c] = best + pl[t * C_ + c];
            }
            bpk[t] = mpack;
            #pragma unroll
            for (int c = 0; c < C_; ++c) a[c] = na[c];
        }
    }

    if (lane == 63) {
        float best = a[0];
        int arg = 0;
        #pragma unroll
        for (int p = 1; p < C_; ++p)
            if (a[p] > best) { best = a[p]; arg = p; }
        s_last = arg;
    }
    if (lane == 0) bpk[0] = 0;
    __syncthreads();

    const int last = s_last;

    unsigned int g = 0u | (1u << 3) | (2u << 6) | (3u << 9) | (4u << 12);
    #pragma unroll
    for (int j = 7; j >= 0; --j) {
        const int t = 8 * lane + j;
        if (t >= 1) {
            const unsigned int m = bpk[t];
            unsigned int ng = 0;
            #pragma unroll
            for (int x = 0; x < C_; ++x) {
                const unsigned int gx = (g >> (3 * x)) & 7u;
                ng |= ((m >> (3 * gx)) & 7u) << (3 * x);
            }
            g = ng;
        }
    }
    gseg[lane] = g;
    __syncthreads();

    if (lane == 0) {
        int cur = last;
        for (int l = 63; l >= 0; --l) {
            bt[l] = cur;
            cur = (int)((gseg[l] >> (3 * cur)) & 7u);
        }
        seqlen[b] = (float)mcnt;
    }
    __syncthreads();

    {
        int tag = bt[lane];
        const int t0 = 8 * lane;
        dec_s[t0 + 7] = tag;
        #pragma unroll
        for (int t = t0 + 7; t >= t0 + 1; --t) {
            tag = (int)((bpk[t] >> (3 * tag)) & 7u);
            dec_s[t - 1] = tag;
        }
    }
    __syncthreads();

    float* db = decoded + b * S_;
    for (int i = lane; i < S_; i += 64) db[i] = (float)dec_s[i];
}

// =========================================================================
extern "C" void kernel_launch(void* const* d_in, const int* in_sizes, int n_in,
                              void* d_out, int out_size, void* d_ws, size_t ws_size,
                              hipStream_t stream) {
    const float* hs    = (const float*)d_in[0];
    const int*   mask  = (const int*)  d_in[1];
    const float* W1    = (const float*)d_in[2];
    const float* b1    = (const float*)d_in[3];
    const float* W2    = (const float*)d_in[4];
    const float* b2    = (const float*)d_in[5];
    const float* chain = (const float*)d_in[6];
    const float* lb    = (const float*)d_in[7];
    const float* rb    = (const float*)d_in[8];

    float* out      = (float*)d_out;
    float* decoded  = out;
    float* pot      = out + M_;
    float* seq      = out + M_ + M_ * C_;
    float* chainout = seq + B_;

    const size_t need_w1 = (size_t)W1T_ELEMS * sizeof(unsigned short);            // 1.18 MB
    const size_t need_all = need_w1 + (size_t)XBF_ELEMS * sizeof(unsigned short); // 51.5 MB

    if (ws_size >= need_all) {
        unsigned short* w1t = (unsigned short*)d_ws;
        unsigned short* xbf = w1t + W1T_ELEMS;
        prep_all_kernel<<<PX_BLOCKS + PW_BLOCKS + PI_BLOCKS, 256, 0, stream>>>(
            hs, W1, b2, lb, rb, xbf, w1t, pot);
        gemm_bk64_kernel<<<1536, 256, 0, stream>>>(xbf, w1t, b1, W2, pot);
    } else if (ws_size >= need_w1) {
        unsigned short* w1t = (unsigned short*)d_ws;
        init_pot_kernel<<<PI_BLOCKS, 256, 0, stream>>>(b2, lb, rb, pot);
        dim3 pgrid(H_ / 32, D_ / 32);
        prep_w1_kernel<<<pgrid, 256, 0, stream>>>(W1, w1t);
        gemm_bf16_kernel<<<1536, 256, 0, stream>>>(hs, w1t, b1, W2, pot);
    } else {
        init_pot_kernel<<<PI_BLOCKS, 256, 0, stream>>>(b2, lb, rb, pot);
        dim3 grid(H_ / 128, M_ / 128);
        gemm_relu_pot_kernel<<<grid, 256, 0, stream>>>(hs, W1, b1, W2, pot);
    }

    viterbi_kernel<<<B_, 64, 0, stream>>>(pot, chain, mask, decoded, seq, chainout);
}